// Round 3
// baseline (1101.088 us; speedup 1.0000x reference)
//
#include <hip/hip_runtime.h>

#define NGRAPH 16
#define NPG    2048
#define NNODE  (NGRAPH*NPG)      // 32768
#define DIN    128
#define DEMB   64
#define NEDGE  (NNODE*16)        // 524288
#define QCAP   4096

__device__ __forceinline__ float wsum(float v) {
    #pragma unroll
    for (int m = 1; m < 64; m <<= 1) v += __shfl_xor(v, m, 64);
    return v;
}
__device__ __forceinline__ float wmax(float v) {
    #pragma unroll
    for (int m = 1; m < 64; m <<= 1) v = fmaxf(v, __shfl_xor(v, m, 64));
    return v;
}

// ---------------- Kernel 1: h = x@W_self, xn = x@W_nei ----------------
__global__ __launch_bounds__(256) void k_inproj(
    const float* __restrict__ x, const float* __restrict__ Wself,
    const float* __restrict__ Wnei, float* __restrict__ h, float* __restrict__ xn)
{
    __shared__ float ws[DIN*DEMB];   // 32 KB
    __shared__ float wn[DIN*DEMB];   // 32 KB
    int tid = threadIdx.x;
    int n0 = blockIdx.x * 32;
    #pragma unroll
    for (int k = 0; k < 8; ++k) {
        ((float4*)ws)[tid + k*256] = ((const float4*)Wself)[tid + k*256];
        ((float4*)wn)[tid + k*256] = ((const float4*)Wnei)[tid + k*256];
    }
    __syncthreads();
    int nl = tid >> 3, og = (tid & 7) * 8;
    const float* xr = x + (size_t)(n0 + nl) * DIN;
    float ah[8] = {0,0,0,0,0,0,0,0};
    float an[8] = {0,0,0,0,0,0,0,0};
    for (int d4 = 0; d4 < DIN/4; ++d4) {
        float4 xv = *(const float4*)(xr + d4*4);
        #pragma unroll
        for (int dd = 0; dd < 4; ++dd) {
            float xs = (dd==0)?xv.x:(dd==1)?xv.y:(dd==2)?xv.z:xv.w;
            int d = d4*4 + dd;
            float4 a = *(const float4*)&ws[d*DEMB + og];
            float4 b = *(const float4*)&ws[d*DEMB + og + 4];
            ah[0] += xs*a.x; ah[1] += xs*a.y; ah[2] += xs*a.z; ah[3] += xs*a.w;
            ah[4] += xs*b.x; ah[5] += xs*b.y; ah[6] += xs*b.z; ah[7] += xs*b.w;
            float4 c = *(const float4*)&wn[d*DEMB + og];
            float4 e = *(const float4*)&wn[d*DEMB + og + 4];
            an[0] += xs*c.x; an[1] += xs*c.y; an[2] += xs*c.z; an[3] += xs*c.w;
            an[4] += xs*e.x; an[5] += xs*e.y; an[6] += xs*e.z; an[7] += xs*e.w;
        }
    }
    size_t o = (size_t)(n0 + nl)*DEMB + og;
    *(float4*)&h[o]    = make_float4(ah[0],ah[1],ah[2],ah[3]);
    *(float4*)&h[o+4]  = make_float4(ah[4],ah[5],ah[6],ah[7]);
    *(float4*)&xn[o]   = make_float4(an[0],an[1],an[2],an[3]);
    *(float4*)&xn[o+4] = make_float4(an[4],an[5],an[6],an[7]);
}

// ---------------- Kernel 2: edge aggregation, LDS-binned (no global atomics) ----------------
__global__ __launch_bounds__(1024) void k_agg(
    const int* __restrict__ ei, const float* __restrict__ xn,
    float* __restrict__ agg, float* __restrict__ deg)
{
    __shared__ float accL[128*64];   // 32 KB
    __shared__ float degL[128];
    __shared__ int   queue[QCAP];    // 16 KB
    __shared__ int   qcnt;
    int tid = threadIdx.x;
    int g   = blockIdx.x >> 4;       // graph
    int dlo = (blockIdx.x & 15) * 128;
    for (int k = tid; k < 128*64; k += 1024) accL[k] = 0.f;
    if (tid < 128) degL[tid] = 0.f;
    if (tid == 0) qcnt = 0;
    __syncthreads();
    int e0 = g * (NPG*16);
    int gbase = g * NPG;
    for (int k = 0; k < 32; ++k) {
        int e = e0 + k*1024 + tid;
        int dst = ei[NEDGE + e];
        int dl = dst - gbase - dlo;
        if ((unsigned)dl < 128u) {
            int src = ei[e];                 // global node id < 32768, fits 16 bits
            int qi = atomicAdd(&qcnt, 1);
            if (qi < QCAP) queue[qi] = (dl << 16) | src;
        }
    }
    __syncthreads();
    int qn = qcnt < QCAP ? qcnt : QCAP;
    int w = tid >> 6, l = tid & 63;
    int i = w;
    for (; i + 48 < qn; i += 64) {
        int p0 = queue[i], p1 = queue[i+16], p2 = queue[i+32], p3 = queue[i+48];
        float v0 = xn[(size_t)(p0 & 0xffff)*64 + l];
        float v1 = xn[(size_t)(p1 & 0xffff)*64 + l];
        float v2 = xn[(size_t)(p2 & 0xffff)*64 + l];
        float v3 = xn[(size_t)(p3 & 0xffff)*64 + l];
        atomicAdd(&accL[(p0 >> 16)*64 + l], v0);
        atomicAdd(&accL[(p1 >> 16)*64 + l], v1);
        atomicAdd(&accL[(p2 >> 16)*64 + l], v2);
        atomicAdd(&accL[(p3 >> 16)*64 + l], v3);
        if (l == 0) {
            atomicAdd(&degL[p0 >> 16], 1.f);
            atomicAdd(&degL[p1 >> 16], 1.f);
            atomicAdd(&degL[p2 >> 16], 1.f);
            atomicAdd(&degL[p3 >> 16], 1.f);
        }
    }
    for (; i < qn; i += 16) {
        int p0 = queue[i];
        float v0 = xn[(size_t)(p0 & 0xffff)*64 + l];
        atomicAdd(&accL[(p0 >> 16)*64 + l], v0);
        if (l == 0) atomicAdd(&degL[p0 >> 16], 1.f);
    }
    __syncthreads();
    size_t obase = (size_t)(gbase + dlo) * 64;
    for (int k = tid; k < 128*64; k += 1024) agg[obase + k] = accL[k];
    if (tid < 128) deg[gbase + dlo + tid] = degL[tid];
}

// ---------------- Kernel 3: x_aux = relu(h + agg/max(deg,1) + b); sq = ||x_aux||^2 ----------------
__global__ __launch_bounds__(256) void k_epi(
    const float* __restrict__ h, const float* __restrict__ agg,
    const float* __restrict__ deg, const float* __restrict__ bias,
    float* __restrict__ xaux, float* __restrict__ sqv)
{
    int w = threadIdx.x >> 6, l = threadIdx.x & 63;
    int n = blockIdx.x*4 + w;
    float dg = fmaxf(deg[n], 1.f);
    float v = h[(size_t)n*64 + l] + agg[(size_t)n*64 + l] / dg + bias[l];
    v = fmaxf(v, 0.f);
    xaux[(size_t)n*64 + l] = v;
    float s = wsum(v*v);
    if (l == 0) sqv[n] = s;
}

// ---------------- Kernel 4: transpose x_aux -> xtg[64][NNODE] ----------------
__global__ __launch_bounds__(256) void k_tr(
    const float* __restrict__ xaux, float* __restrict__ xtg)
{
    __shared__ float tl[64*65];
    int tid = threadIdx.x;
    int n0 = blockIdx.x * 64;
    #pragma unroll
    for (int k = 0; k < 16; ++k) {
        int e = tid + k*256;
        tl[(e >> 6)*65 + (e & 63)] = xaux[(size_t)n0*64 + e];
    }
    __syncthreads();
    #pragma unroll
    for (int k = 0; k < 16; ++k) {
        int f = tid + k*256;
        xtg[(size_t)(f >> 6)*NNODE + n0 + (f & 63)] = tl[(f & 63)*65 + (f >> 6)];
    }
}

// ---------------- Kernel 5: fused pairwise distance + noise + layernorm-ish + entmax15 ----------------
// Block: 512 threads (8 waves), 8 rows of one graph. Phase 1: GEMM layout (wave = j-quarter,
// lane holds 4 consecutive j, 8 rows in acc[8][4]). Transition via 32KB LDS (2 rounds) to
// phase-2 layout: wave w owns row w, lane holds j = 256k + 4l + c. All reductions are
// wave-local shfl butterflies (no barriers).
#define PFMA(R, XI) { float xs_ = (XI); acc[R][0] += xs_*xj.x; acc[R][1] += xs_*xj.y; acc[R][2] += xs_*xj.z; acc[R][3] += xs_*xj.w; }

__global__ __launch_bounds__(512, 4) void k_pair(
    const float* __restrict__ xtg, const float* __restrict__ xaux,
    const float* __restrict__ sq, const float* __restrict__ noise,
    float* __restrict__ outA, float* __restrict__ outL)
{
    __shared__ float buf[4*2048];    // 32 KB transition buffer
    __shared__ float xit[64*8];      // x_i rows, d-major
    __shared__ float sqi[8];
    int tid = threadIdx.x;
    int b  = blockIdx.x >> 8;
    int r0 = (blockIdx.x & 255) << 3;
    {
        int r = tid & 7, d = tid >> 3;
        xit[d*8 + r] = xaux[(size_t)(b*NPG + r0 + r)*64 + d];
        if (tid < 8) sqi[tid] = sq[b*NPG + r0 + tid];
    }
    __syncthreads();
    int w = tid >> 6, l = tid & 63;
    int jb = b*NPG + (w << 8) + (l << 2);

    float acc[8][4];
    #pragma unroll
    for (int r = 0; r < 8; ++r) { acc[r][0]=0.f; acc[r][1]=0.f; acc[r][2]=0.f; acc[r][3]=0.f; }

    const float* xp = xtg + jb;
    #pragma unroll 4
    for (int d = 0; d < 64; ++d) {
        float4 xj  = *(const float4*)(xp + (size_t)d*NNODE);
        float4 xiA = *(const float4*)&xit[d*8];
        float4 xiB = *(const float4*)&xit[d*8 + 4];
        PFMA(0, xiA.x) PFMA(1, xiA.y) PFMA(2, xiA.z) PFMA(3, xiA.w)
        PFMA(4, xiB.x) PFMA(5, xiB.y) PFMA(6, xiB.z) PFMA(7, xiB.w)
    }

    // logits = -sqrt(clip(sq_i + sq_j - 2*dot, 0) + 1e-12) + noise (in-place in acc)
    float4 sj = *(const float4*)&sq[jb];
    #pragma unroll
    for (int r = 0; r < 8; ++r) {
        float4 nz = *(const float4*)(noise + (size_t)(b*NPG + r0 + r)*NPG + (w << 8) + (l << 2));
        float si = sqi[r];
        acc[r][0] = nz.x - sqrtf(fmaxf(si + sj.x - 2.f*acc[r][0], 0.f) + 1e-12f);
        acc[r][1] = nz.y - sqrtf(fmaxf(si + sj.y - 2.f*acc[r][1], 0.f) + 1e-12f);
        acc[r][2] = nz.z - sqrtf(fmaxf(si + sj.z - 2.f*acc[r][2], 0.f) + 1e-12f);
        acc[r][3] = nz.w - sqrtf(fmaxf(si + sj.w - 2.f*acc[r][3], 0.f) + 1e-12f);
    }

    // transition to wave-per-row layout (two 4-row rounds through 32KB LDS)
    int col = (w << 8) + (l << 2);
    float z[8][4];
    int wr = w & 3;
    #pragma unroll
    for (int r = 0; r < 4; ++r)
        *(float4*)&buf[r*2048 + col] = make_float4(acc[r][0],acc[r][1],acc[r][2],acc[r][3]);
    __syncthreads();
    if (w < 4) {
        #pragma unroll
        for (int k = 0; k < 8; ++k) {
            float4 t = *(const float4*)&buf[wr*2048 + k*256 + (l << 2)];
            z[k][0]=t.x; z[k][1]=t.y; z[k][2]=t.z; z[k][3]=t.w;
        }
    }
    __syncthreads();
    #pragma unroll
    for (int r = 0; r < 4; ++r)
        *(float4*)&buf[r*2048 + col] = make_float4(acc[r+4][0],acc[r+4][1],acc[r+4][2],acc[r+4][3]);
    __syncthreads();
    if (w >= 4) {
        #pragma unroll
        for (int k = 0; k < 8; ++k) {
            float4 t = *(const float4*)&buf[wr*2048 + k*256 + (l << 2)];
            z[k][0]=t.x; z[k][1]=t.y; z[k][2]=t.z; z[k][3]=t.w;
        }
    }

    // row stats (wave-local): mu, sd (two-pass), max — on logits
    float s = 0.f;
    #pragma unroll
    for (int k = 0; k < 8; ++k) { s += z[k][0]; s += z[k][1]; s += z[k][2]; s += z[k][3]; }
    s = wsum(s);
    float mu = s * (1.f/2048.f);
    float vs = 0.f;
    #pragma unroll
    for (int k = 0; k < 8; ++k) {
        #pragma unroll
        for (int c = 0; c < 4; ++c) { float t = z[k][c] - mu; vs += t*t; }
    }
    vs = wsum(vs);
    float sd = sqrtf(vs * (1.f/2048.f));
    float mx = -1e30f;
    #pragma unroll
    for (int k = 0; k < 8; ++k) {
        #pragma unroll
        for (int c = 0; c < 4; ++c) mx = fmaxf(mx, z[k][c]);
    }
    mx = wmax(mx);

    // z = 0.5*GAMMA*(lg - mu)/(sd+1e-5) - max(...) == cc*(lg - lgmax)
    float cc = 2.5f / (sd + 1e-5f);
    #pragma unroll
    for (int k = 0; k < 8; ++k) {
        #pragma unroll
        for (int c = 0; c < 4; ++c) z[k][c] = cc * (z[k][c] - mx);
    }

    // candidate extraction: only z > -1 can ever be in support (tau* >= zmax-1 = -1)
    float c0=-2.f, c1=-2.f, c2=-2.f, c3=-2.f; int cnt = 0;
    #pragma unroll
    for (int k = 0; k < 8; ++k) {
        #pragma unroll
        for (int c = 0; c < 4; ++c) {
            float zv = z[k][c];
            bool p = zv > -1.f;
            c3 = p ? c2 : c3; c2 = p ? c1 : c2; c1 = p ? c0 : c1; c0 = p ? zv : c0;
            cnt += p ? 1 : 0;
        }
    }
    unsigned long long ovf = __ballot(cnt > 4);

    // bisection on S(tau) = sum max(z-tau,0)^2 = 1, tau in [-1, 0]
    float lo = -1.f, hi = 0.f;
    if (ovf == 0ull) {
        for (int it = 0; it < 25; ++it) {
            float mid = 0.5f*(lo+hi);
            float p, S;
            p = fmaxf(c0-mid,0.f); S  = p*p;
            p = fmaxf(c1-mid,0.f); S += p*p;
            p = fmaxf(c2-mid,0.f); S += p*p;
            p = fmaxf(c3-mid,0.f); S += p*p;
            S = wsum(S);
            bool ge = S >= 1.f;
            lo = ge ? mid : lo; hi = ge ? hi : mid;
        }
    } else {
        for (int it = 0; it < 25; ++it) {
            float mid = 0.5f*(lo+hi);
            float S = 0.f;
            #pragma unroll
            for (int k = 0; k < 8; ++k) {
                #pragma unroll
                for (int c = 0; c < 4; ++c) { float p = fmaxf(z[k][c]-mid, 0.f); S += p*p; }
            }
            S = wsum(S);
            bool ge = S >= 1.f;
            lo = ge ? mid : lo; hi = ge ? hi : mid;
        }
    }
    float tmid = 0.5f*(lo+hi);

    // exact tau from identified support (reference's closed form)
    float k1 = 0.f, s1 = 0.f, q1 = 0.f;
    if (ovf == 0ull) {
        bool in;
        in = c0 > tmid; k1 += in?1.f:0.f; s1 += in?c0:0.f; q1 += in?c0*c0:0.f;
        in = c1 > tmid; k1 += in?1.f:0.f; s1 += in?c1:0.f; q1 += in?c1*c1:0.f;
        in = c2 > tmid; k1 += in?1.f:0.f; s1 += in?c2:0.f; q1 += in?c2*c2:0.f;
        in = c3 > tmid; k1 += in?1.f:0.f; s1 += in?c3:0.f; q1 += in?c3*c3:0.f;
    } else {
        #pragma unroll
        for (int k = 0; k < 8; ++k) {
            #pragma unroll
            for (int c = 0; c < 4; ++c) {
                float zv = z[k][c];
                bool in = zv > tmid;
                k1 += in?1.f:0.f; s1 += in?zv:0.f; q1 += in?zv*zv:0.f;
            }
        }
    }
    k1 = wsum(k1); s1 = wsum(s1); q1 = wsum(q1);
    float kin  = 1.f / k1;
    float mean = s1 * kin;
    float ssv  = q1 - s1*s1*kin;
    float tau  = mean - sqrtf(fmaxf((1.f - ssv)*kin, 0.f));

    // outputs: A = clip(z - tau, 0)^2 ; logprobs = log(A + 1e-6)
    size_t ro = (size_t)(b*NPG + r0 + w) * NPG;
    #pragma unroll
    for (int k = 0; k < 8; ++k) {
        float a0, a1, a2, a3, p;
        p = fmaxf(z[k][0]-tau, 0.f); a0 = p*p;
        p = fmaxf(z[k][1]-tau, 0.f); a1 = p*p;
        p = fmaxf(z[k][2]-tau, 0.f); a2 = p*p;
        p = fmaxf(z[k][3]-tau, 0.f); a3 = p*p;
        *(float4*)&outA[ro + k*256 + (l << 2)] = make_float4(a0,a1,a2,a3);
        *(float4*)&outL[ro + k*256 + (l << 2)] =
            make_float4(__logf(a0+1e-6f), __logf(a1+1e-6f), __logf(a2+1e-6f), __logf(a3+1e-6f));
    }
}

// ---------------- host ----------------
extern "C" void kernel_launch(void* const* d_in, const int* in_sizes, int n_in,
                              void* d_out, int out_size, void* d_ws, size_t ws_size,
                              hipStream_t stream)
{
    (void)in_sizes; (void)n_in; (void)out_size; (void)ws_size;
    const float* x     = (const float*)d_in[0];
    const int*   ei    = (const int*)d_in[1];
    const float* Wself = (const float*)d_in[4];
    const float* Wnei  = (const float*)d_in[5];
    const float* bias  = (const float*)d_in[6];
    const float* noise = (const float*)d_in[7];
    float* out = (float*)d_out;
    float* ws  = (float*)d_ws;

    // ws layout (floats), peak ~25.4 MB:
    //   h[2M] xn[2M] agg[2M] deg[32K] sq[32K]
    // xtg ALIASES h: k_epi (last reader of h) completes before k_tr writes xtg
    // (same-stream ordering), so the slot is safely reused.
    float* h    = ws;
    float* xn   = ws + 2097152;
    float* agg  = ws + 4194304;
    float* deg  = ws + 6291456;
    float* sqv  = ws + 6324224;
    float* xtg  = h;                   // alias (see above)

    float* xaux = out;                 // [32768][64]
    float* outA = out + 2097152;       // [16][2048][2048]
    float* outL = out + 69206016;      // [16][2048][2048]

    hipLaunchKernelGGL(k_inproj, dim3(1024), dim3(256), 0, stream, x, Wself, Wnei, h, xn);
    hipLaunchKernelGGL(k_agg,    dim3(256),  dim3(1024), 0, stream, ei, xn, agg, deg);
    hipLaunchKernelGGL(k_epi,    dim3(8192), dim3(256), 0, stream, h, agg, deg, bias, xaux, sqv);
    hipLaunchKernelGGL(k_tr,     dim3(512),  dim3(256), 0, stream, xaux, xtg);
    hipLaunchKernelGGL(k_pair,   dim3(4096), dim3(512), 0, stream, xtg, xaux, sqv, noise, outA, outL);
}